// Round 13
// baseline (420.807 us; speedup 1.0000x reference)
//
#include <hip/hip_runtime.h>
#include <hip/hip_fp16.h>

#define CH 256
#define HW 4096
#define K_TOP 115
#define CAND 128
#define TPAD 152   // u16 row stride: 304B; 4-row offset = 16 mod 32 -> 2-way (free); rows 16B-aligned
#define NTRI 528   // 32*33/2 upper-triangle 128x128 tiles per batch
#define NTRI_H 264 // half-triangle per XCD

typedef __attribute__((ext_vector_type(8))) short short8;
typedef __attribute__((ext_vector_type(4))) float f32x4;
typedef __attribute__((ext_vector_type(4))) unsigned int u32x4;

__device__ __forceinline__ unsigned short f32_to_bf16(float f) {
  union { float f; unsigned int u; } v; v.f = f;
  unsigned int r = v.u + 0x7fffu + ((v.u >> 16) & 1u);
  return (unsigned short)(r >> 16);
}

__device__ __forceinline__ unsigned int f16key(unsigned short h) {
  return (h & 0x8000u) ? (unsigned int)((unsigned short)~h)
                       : (unsigned int)(h | 0x8000u);
}

__device__ __forceinline__ unsigned short key2f16(unsigned int k) {
  return (k & 0x8000u) ? (unsigned short)(k ^ 0x8000u)
                       : (unsigned short)(~k & 0xffffu);
}

// ---------- kernel 1a: rn[b][p] = 1 / max(||x[b,:,p]||, eps) ----------
__global__ void norms_kernel(const float* __restrict__ x, float* __restrict__ rn) {
  int b = blockIdx.x >> 4;
  int p = ((blockIdx.x & 15) << 8) + threadIdx.x;
  const float* xb = x + (size_t)b * CH * HW + p;
  float ss = 0.f;
  #pragma unroll 8
  for (int c = 0; c < CH; ++c) { float v = xb[(size_t)c * HW]; ss += v * v; }
  rn[b * HW + p] = 1.0f / fmaxf(sqrtf(ss), 1e-12f);
}

// ---------- kernel 1b: xnT[b][p][c] = bf16(x[b][c][p] * rn[b][p]) ----------
__global__ void transpose_kernel(const float* __restrict__ x, const float* __restrict__ rn,
                                 unsigned short* __restrict__ xnT) {
  __shared__ float tile[64][65];
  int blk = blockIdx.x;
  int b = blk >> 8;
  int rem = blk & 255;
  int c0 = (rem >> 6) << 6;
  int p0 = (rem & 63) << 6;
  for (int idx = threadIdx.x; idx < 64 * 64; idx += blockDim.x) {
    int c = idx >> 6, p = idx & 63;
    tile[c][p] = x[((size_t)b * CH + c0 + c) * HW + p0 + p];
  }
  __syncthreads();
  for (int idx = threadIdx.x; idx < 64 * 64; idx += blockDim.x) {
    int p = idx >> 6, c = idx & 63;
    xnT[((size_t)b * HW + p0 + p) * CH + c0 + c] =
        f32_to_bf16(tile[c][p] * rn[b * HW + p0 + p]);
  }
}

// ---------- kernel A: symmetric Gram -> u16 keys (row-major per batch) ----------
// 64-row LDS tile (19.4KB) -> 8 blocks/CU (was 4 at 38.9KB): doubles waves &
// loads-in-flight to cover L2-hit latency (R12: all pipes <10%, Occ 36% ->
// latency-bound). Epilogue split into half-tile passes. nt stores keep the
// write stream out of L2 (R12: FETCH 24->11.8MB).
__launch_bounds__(256, 8)
__global__ void gram_kernel(const unsigned short* __restrict__ xnT,
                            unsigned short* __restrict__ gkeys, int nb) {
  __shared__ unsigned short tile[64 * TPAD];
  const int tid  = threadIdx.x;
  const int lane = tid & 63, wv = tid >> 6;
  const int wj = wv >> 1, wi = wv & 1;
  const int lr = lane & 15, lk = lane >> 4;

  int bb, t;
  if (nb == 4) {
    const int xcd = blockIdx.x & 7;
    bb = xcd >> 1;
    t  = ((xcd & 1) ? NTRI_H : 0) + (blockIdx.x >> 3);
  } else {
    bb = 0;
    t  = blockIdx.x;
  }
  int it = (int)((sqrtf(8.0f * (float)t + 1.0f) - 1.0f) * 0.5f);
  while (((it + 1) * (it + 2)) / 2 <= t) ++it;
  while ((it * (it + 1)) / 2 > t) --it;
  const int jt = t - (it * (it + 1)) / 2;  // jt <= it
  const int j0 = jt * 128, i0 = it * 128;

  const short8* x8 = (const short8*)(xnT + (size_t)bb * HW * CH);
  unsigned short* gk = gkeys + (size_t)bb * HW * HW;

  f32x4 acc[4][4];
  #pragma unroll
  for (int m = 0; m < 4; ++m)
    #pragma unroll
    for (int n = 0; n < 4; ++n) acc[m][n] = (f32x4){0.f, 0.f, 0.f, 0.f};

  const int jbase = j0 + wj * 64 + lr;
  const int ibase = i0 + wi * 64 + lr;
  #pragma unroll
  for (int kk = 0; kk < 8; ++kk) {
    short8 af[4], bf[4];
    #pragma unroll
    for (int m = 0; m < 4; ++m)
      af[m] = x8[(size_t)(jbase + m * 16) * 32 + kk * 4 + lk];
    #pragma unroll
    for (int n = 0; n < 4; ++n)
      bf[n] = x8[(size_t)(ibase + n * 16) * 32 + kk * 4 + lk];
    #pragma unroll
    for (int m = 0; m < 4; ++m)
      #pragma unroll
      for (int n = 0; n < 4; ++n)
        acc[m][n] = __builtin_amdgcn_mfma_f32_16x16x32_bf16(af[m], bf[n],
                                                            acc[m][n], 0, 0, 0);
  }

  // ---- epilogue: half-tile passes through a 64-row LDS buffer ----
  // Normal orientation: rows jloc = wj*64 + m*16 + lk*4 + r; wj selects half.
  #define WRITE_NORMAL(WJ)                                                     \
    if (wj == (WJ)) {                                                          \
      _Pragma("unroll")                                                        \
      for (int m = 0; m < 4; ++m) {                                            \
        _Pragma("unroll")                                                      \
        for (int n = 0; n < 4; ++n) {                                          \
          _Pragma("unroll")                                                    \
          for (int r = 0; r < 4; ++r) {                                        \
            int jloc = m * 16 + lk * 4 + r;                                    \
            int iloc = wi * 64 + n * 16 + lr;                                  \
            tile[jloc * TPAD + iloc] = (unsigned short)f16key(                 \
                __half_as_ushort(__float2half(acc[m][n][r])));                 \
          }                                                                    \
        }                                                                      \
      }                                                                        \
    }
  // Mirror (transposed): rows il = wi*64 + n*16 + lr; wi selects half.
  #define WRITE_MIRROR(WI)                                                     \
    if (wi == (WI)) {                                                          \
      _Pragma("unroll")                                                        \
      for (int m = 0; m < 4; ++m) {                                            \
        _Pragma("unroll")                                                      \
        for (int n = 0; n < 4; ++n) {                                          \
          int il  = n * 16 + lr;                                               \
          int jl0 = wj * 64 + m * 16 + lk * 4;                                 \
          unsigned long long pk =                                              \
              (unsigned long long)f16key(__half_as_ushort(__float2half(acc[m][n][0]))) |        \
              ((unsigned long long)f16key(__half_as_ushort(__float2half(acc[m][n][1]))) << 16) |\
              ((unsigned long long)f16key(__half_as_ushort(__float2half(acc[m][n][2]))) << 32) |\
              ((unsigned long long)f16key(__half_as_ushort(__float2half(acc[m][n][3]))) << 48); \
          *(unsigned long long*)&tile[il * TPAD + jl0] = pk;                   \
        }                                                                      \
      }                                                                        \
    }
  // Store 64 rows starting at gk row base RB, column base CB.
  #define STORE_HALF(RB, CB)                                                   \
    _Pragma("unroll")                                                          \
    for (int itr = 0; itr < 4; ++itr) {                                        \
      int idx = itr * 256 + tid;                                               \
      int row = idx >> 4, ch = idx & 15;                                       \
      u32x4 v = *(const u32x4*)&tile[row * TPAD + ch * 8];                     \
      __builtin_nontemporal_store(                                             \
          v, (u32x4*)(gk + (size_t)((RB) + row) * HW + (CB) + ch * 8));        \
    }

  WRITE_NORMAL(0)
  __syncthreads();
  STORE_HALF(j0, i0)
  __syncthreads();
  WRITE_NORMAL(1)
  __syncthreads();
  STORE_HALF(j0 + 64, i0)

  if (it != jt) {
    __syncthreads();
    WRITE_MIRROR(0)
    __syncthreads();
    STORE_HALF(i0, j0)
    __syncthreads();
    WRITE_MIRROR(1)
    __syncthreads();
    STORE_HALF(i0 + 64, j0)
  }
  #undef WRITE_NORMAL
  #undef WRITE_MIRROR
  #undef STORE_HALF
}

// ---------- kernel B: per-column top-115, SWAR packed counting ----------
// Keys stay PACKED in 8 u32x4 (32 VGPRs — register-resident, R11 verified).
// Corr in [-1.008,1.008] => keys in 15-bit space after -0x4000.
__launch_bounds__(256, 4)
__global__ void select_kernel(const unsigned short* __restrict__ gkeys,
                              float* __restrict__ out, int b_base, int nb) {
  __shared__ unsigned short cand[4][CAND];
  __shared__ unsigned int cnt[4];
  const int tid  = threadIdx.x;
  const int lane = tid & 63, wv = tid >> 6;
  int bb, cg;
  if (nb == 4) {
    const int xcd = blockIdx.x & 7;
    bb = xcd >> 1;
    cg = ((xcd & 1) << 9) + (blockIdx.x >> 3);   // [0,1024)
  } else {
    bb = 0;
    cg = blockIdx.x;
  }
  const int b = b_base + bb;
  const int j = cg * 4 + wv;

  const u32x4* cp4 = (const u32x4*)(gkeys + (size_t)bb * HW * HW + (size_t)j * HW);
  u32x4 q0 = cp4[0 * 64 + lane], q1 = cp4[1 * 64 + lane];
  u32x4 q2 = cp4[2 * 64 + lane], q3 = cp4[3 * 64 + lane];
  u32x4 q4 = cp4[4 * 64 + lane], q5 = cp4[5 * 64 + lane];
  u32x4 q6 = cp4[6 * 64 + lane], q7 = cp4[7 * 64 + lane];

  // one-time SWAR transform (keys remain recoverable: half & 0x7fff)
  q0 = (q0 - 0x40004000u) | 0x80008000u;
  q1 = (q1 - 0x40004000u) | 0x80008000u;
  q2 = (q2 - 0x40004000u) | 0x80008000u;
  q3 = (q3 - 0x40004000u) | 0x80008000u;
  q4 = (q4 - 0x40004000u) | 0x80008000u;
  q5 = (q5 - 0x40004000u) | 0x80008000u;
  q6 = (q6 - 0x40004000u) | 0x80008000u;
  q7 = (q7 - 0x40004000u) | 0x80008000u;

  // binary search in 15-bit space: lo = max v with #{k15 >= v} >= 115
  unsigned int lo = 0;
  #pragma unroll 1
  for (int bit = 14; bit >= 0; --bit) {
    const unsigned int m  = lo | (1u << bit);
    const unsigned int mm = m * 0x10001u;
    int c = 0;
    #define CNTV(Q) \
      c += (int)__builtin_popcount((Q.x - mm) & 0x80008000u); \
      c += (int)__builtin_popcount((Q.y - mm) & 0x80008000u); \
      c += (int)__builtin_popcount((Q.z - mm) & 0x80008000u); \
      c += (int)__builtin_popcount((Q.w - mm) & 0x80008000u);
    CNTV(q0) CNTV(q1) CNTV(q2) CNTV(q3)
    CNTV(q4) CNTV(q5) CNTV(q6) CNTV(q7)
    #undef CNTV
    c += __shfl_xor(c, 1);
    c += __shfl_xor(c, 2);
    c += __shfl_xor(c, 4);
    c += __shfl_xor(c, 8);
    c += __shfl_xor(c, 16);
    c += __shfl_xor(c, 32);
    if (c >= K_TOP) lo = m;
  }

  // prefill candidates with threshold (15-bit values; u16-typed — TBAA!)
  cand[wv][2 * lane]     = (unsigned short)lo;
  cand[wv][2 * lane + 1] = (unsigned short)lo;
  if (lane == 0) cnt[wv] = 0;

  // scatter strictly-greater 15-bit keys (<=114 guaranteed)
  #define GATH(v)                                                \
    { unsigned int _v = (v);                                     \
      if (_v > lo) {                                             \
        unsigned int _p = atomicAdd(&cnt[wv], 1u);               \
        cand[wv][_p] = (unsigned short)_v;                       \
      } }
  #define GATH4(Q)                                               \
    GATH(Q.x & 0x7fffu) GATH((Q.x >> 16) & 0x7fffu)              \
    GATH(Q.y & 0x7fffu) GATH((Q.y >> 16) & 0x7fffu)              \
    GATH(Q.z & 0x7fffu) GATH((Q.z >> 16) & 0x7fffu)              \
    GATH(Q.w & 0x7fffu) GATH((Q.w >> 16) & 0x7fffu)
  GATH4(q0) GATH4(q1) GATH4(q2) GATH4(q3)
  GATH4(q4) GATH4(q5) GATH4(q6) GATH4(q7)
  #undef GATH4
  #undef GATH

  asm volatile("" ::: "memory");  // scatter stores before read-back

  // rank-by-count over 128 candidates (unique composite keys -> unique ranks)
  unsigned int k0 = cand[wv][2 * lane];
  unsigned int k1 = cand[wv][2 * lane + 1];
  unsigned int c0 = (k0 << 7) | (127u - (unsigned)(2 * lane));
  unsigned int c1 = (k1 << 7) | (127u - (unsigned)(2 * lane + 1));
  int r0 = 0, r1 = 0;
  #pragma unroll 1
  for (int sl = 0; sl < 64; ++sl) {
    unsigned int d0 = __shfl(c0, sl);
    unsigned int d1 = __shfl(c1, sl);
    r0 += (int)(d0 > c0) + (int)(d1 > c0);
    r1 += (int)(d0 > c1) + (int)(d1 > c1);
  }
  if (r0 < K_TOP)
    out[((size_t)b * K_TOP + r0) * HW + j] =
        __half2float(__ushort_as_half(key2f16(k0 + 0x4000u))) * (1.0f / 256.0f);
  if (r1 < K_TOP)
    out[((size_t)b * K_TOP + r1) * HW + j] =
        __half2float(__ushort_as_half(key2f16(k1 + 0x4000u))) * (1.0f / 256.0f);
}

extern "C" void kernel_launch(void* const* d_in, const int* in_sizes, int n_in,
                              void* d_out, int out_size, void* d_ws, size_t ws_size,
                              hipStream_t stream) {
  (void)in_sizes; (void)n_in; (void)out_size;
  const float* x = (const float*)d_in[0];
  float* out = (float*)d_out;
  float* rn = (float*)d_ws;                                       // 64 KB
  unsigned short* xnT = (unsigned short*)((char*)d_ws + 65536);   // 8 MB bf16
  const size_t GK_OFF = 65536 + (size_t)8 * 1024 * 1024;
  const size_t ONE    = (size_t)HW * HW * 2;                      // 32 MB / batch
  const size_t NEED_1 = GK_OFF + ONE;
  const size_t NEED_4 = GK_OFF + 4 * ONE;                         // 136 MB

  norms_kernel<<<64, 256, 0, stream>>>(x, rn);
  transpose_kernel<<<1024, 256, 0, stream>>>(x, rn, xnT);

  if (ws_size >= NEED_4) {
    unsigned short* gkeys = (unsigned short*)((char*)d_ws + GK_OFF);
    gram_kernel<<<4 * NTRI, 256, 0, stream>>>(xnT, gkeys, 4);
    select_kernel<<<4096, 256, 0, stream>>>(gkeys, out, 0, 4);
  } else if (ws_size >= NEED_1) {
    unsigned short* gkeys = (unsigned short*)((char*)d_ws + GK_OFF);
    for (int b = 0; b < 4; ++b) {
      gram_kernel<<<NTRI, 256, 0, stream>>>(xnT + (size_t)b * HW * CH, gkeys, 1);
      select_kernel<<<1024, 256, 0, stream>>>(gkeys, out, b, 1);
    }
  }
}

// Round 14
// 136.480 us; speedup vs baseline: 3.0833x; 3.0833x over previous
//
#include <hip/hip_runtime.h>
#include <hip/hip_fp16.h>

#define CH 256
#define HW 4096
#define K_TOP 115
#define CAND 128
#define TPAD 152   // u16 row stride: 304B; 4-row offset = 16 mod 32 -> 2-way (free); rows 16B-aligned
#define NTRI 528   // 32*33/2 upper-triangle 128x128 tiles per batch
#define NTRI_H 264 // half-triangle per XCD

typedef __attribute__((ext_vector_type(8))) short short8;
typedef __attribute__((ext_vector_type(4))) float f32x4;
typedef __attribute__((ext_vector_type(4))) unsigned int u32x4;

__device__ __forceinline__ unsigned short f32_to_bf16(float f) {
  union { float f; unsigned int u; } v; v.f = f;
  unsigned int r = v.u + 0x7fffu + ((v.u >> 16) & 1u);
  return (unsigned short)(r >> 16);
}

__device__ __forceinline__ unsigned int f16key(unsigned short h) {
  return (h & 0x8000u) ? (unsigned int)((unsigned short)~h)
                       : (unsigned int)(h | 0x8000u);
}

__device__ __forceinline__ unsigned short key2f16(unsigned int k) {
  return (k & 0x8000u) ? (unsigned short)(k ^ 0x8000u)
                       : (unsigned short)(~k & 0xffffu);
}

// ---------- kernel 1a: rn[b][p] = 1 / max(||x[b,:,p]||, eps) ----------
__global__ void norms_kernel(const float* __restrict__ x, float* __restrict__ rn) {
  int b = blockIdx.x >> 4;
  int p = ((blockIdx.x & 15) << 8) + threadIdx.x;
  const float* xb = x + (size_t)b * CH * HW + p;
  float ss = 0.f;
  #pragma unroll 8
  for (int c = 0; c < CH; ++c) { float v = xb[(size_t)c * HW]; ss += v * v; }
  rn[b * HW + p] = 1.0f / fmaxf(sqrtf(ss), 1e-12f);
}

// ---------- kernel 1b: xnT in FRAGMENT-MAJOR layout ----------
// xnT[b][pg:256][kk:8][lane:64] = 16B entry: pixel pg*16+(lane&15),
// channels kk*32+(lane>>4)*8 .. +8, bf16. A wave's MFMA fragment load is
// then 64 lanes x 16B CONTIGUOUS (1KB) — the old [p][c] layout had lane
// stride 512B => 16 scattered segments per load, saturating the per-CU TA
// (R6-R12: per-block time ~10us invariant to occupancy/caching).
__global__ void transpose_kernel(const float* __restrict__ x, const float* __restrict__ rn,
                                 unsigned short* __restrict__ xnT) {
  __shared__ float tile[64][65];   // [c_local][p_local]
  int blk = blockIdx.x;
  int b = blk >> 8;
  int rem = blk & 255;
  int c0 = (rem >> 6) << 6;
  int p0 = (rem & 63) << 6;
  for (int idx = threadIdx.x; idx < 64 * 64; idx += blockDim.x) {
    int c = idx >> 6, p = idx & 63;
    tile[c][p] = x[((size_t)b * CH + c0 + c) * HW + p0 + p];
  }
  __syncthreads();
  // 512 entries per (64c x 64p) chunk; each = 8 channels of one pixel.
  for (int E = threadIdx.x; E < 512; E += blockDim.x) {
    int lr  = E & 15;
    int lk  = (E >> 4) & 3;
    int kkl = (E >> 6) & 1;
    int pgl = E >> 7;
    int pl = pgl * 16 + lr;
    int cl = kkl * 32 + lk * 8;
    float s = rn[b * HW + p0 + pl];
    unsigned int w0, w1, w2, w3;
    w0 = (unsigned int)f32_to_bf16(tile[cl + 0][pl] * s) |
         ((unsigned int)f32_to_bf16(tile[cl + 1][pl] * s) << 16);
    w1 = (unsigned int)f32_to_bf16(tile[cl + 2][pl] * s) |
         ((unsigned int)f32_to_bf16(tile[cl + 3][pl] * s) << 16);
    w2 = (unsigned int)f32_to_bf16(tile[cl + 4][pl] * s) |
         ((unsigned int)f32_to_bf16(tile[cl + 5][pl] * s) << 16);
    w3 = (unsigned int)f32_to_bf16(tile[cl + 6][pl] * s) |
         ((unsigned int)f32_to_bf16(tile[cl + 7][pl] * s) << 16);
    u32x4 w = {w0, w1, w2, w3};
    int pg  = (p0 >> 4) + pgl;
    int kkg = (c0 >> 5) + kkl;
    *(u32x4*)(xnT + ((((size_t)b * 256 + pg) * 8 + kkg) * 64 + lk * 16 + lr) * 8) = w;
  }
}

// ---------- kernel A: symmetric Gram -> u16 keys (row-major per batch) ----------
// Fragment loads are now fully contiguous 1KB per instruction.
__launch_bounds__(256, 4)
__global__ void gram_kernel(const unsigned short* __restrict__ xnT,
                            unsigned short* __restrict__ gkeys, int nb) {
  __shared__ unsigned short tile[128 * TPAD];
  const int tid  = threadIdx.x;
  const int lane = tid & 63, wv = tid >> 6;
  const int wj = wv >> 1, wi = wv & 1;
  const int lr = lane & 15, lk = lane >> 4;

  int bb, t;
  if (nb == 4) {
    const int xcd = blockIdx.x & 7;
    bb = xcd >> 1;
    t  = ((xcd & 1) ? NTRI_H : 0) + (blockIdx.x >> 3);
  } else {
    bb = 0;
    t  = blockIdx.x;
  }
  int it = (int)((sqrtf(8.0f * (float)t + 1.0f) - 1.0f) * 0.5f);
  while (((it + 1) * (it + 2)) / 2 <= t) ++it;
  while ((it * (it + 1)) / 2 > t) --it;
  const int jt = t - (it * (it + 1)) / 2;  // jt <= it
  const int j0 = jt * 128, i0 = it * 128;

  const short8* x8 = (const short8*)(xnT + (size_t)bb * HW * CH);
  unsigned short* gk = gkeys + (size_t)bb * HW * HW;

  f32x4 acc[4][4];
  #pragma unroll
  for (int m = 0; m < 4; ++m)
    #pragma unroll
    for (int n = 0; n < 4; ++n) acc[m][n] = (f32x4){0.f, 0.f, 0.f, 0.f};

  // fragment-major: entry ((pg*8 + kk)*64 + lane), pg = pixel/16
  const int pgj = jt * 8 + wj * 4;   // af pixel-groups pgj..pgj+3
  const int pgi = it * 8 + wi * 4;   // bf pixel-groups pgi..pgi+3
  #pragma unroll
  for (int kk = 0; kk < 8; ++kk) {
    short8 af[4], bf[4];
    #pragma unroll
    for (int m = 0; m < 4; ++m)
      af[m] = x8[(size_t)((pgj + m) * 8 + kk) * 64 + lane];
    #pragma unroll
    for (int n = 0; n < 4; ++n)
      bf[n] = x8[(size_t)((pgi + n) * 8 + kk) * 64 + lane];
    #pragma unroll
    for (int m = 0; m < 4; ++m)
      #pragma unroll
      for (int n = 0; n < 4; ++n)
        acc[m][n] = __builtin_amdgcn_mfma_f32_16x16x32_bf16(af[m], bf[n],
                                                            acc[m][n], 0, 0, 0);
  }

  // phase 1: keys -> tile[jloc][iloc]  (D row = j, D col = i)
  #pragma unroll
  for (int m = 0; m < 4; ++m) {
    #pragma unroll
    for (int n = 0; n < 4; ++n) {
      #pragma unroll
      for (int r = 0; r < 4; ++r) {
        int jloc = wj * 64 + m * 16 + lk * 4 + r;
        int iloc = wi * 64 + n * 16 + lr;
        tile[jloc * TPAD + iloc] =
            (unsigned short)f16key(__half_as_ushort(__float2half(acc[m][n][r])));
      }
    }
  }
  __syncthreads();

  // store 1: rows j of gk (coalesced 16B chunks)
  #pragma unroll
  for (int itr = 0; itr < 8; ++itr) {
    int idx = itr * 256 + tid;
    int row = idx >> 4, ch = idx & 15;
    u32x4 v = *(const u32x4*)&tile[row * TPAD + ch * 8];
    *(u32x4*)(gk + (size_t)(j0 + row) * HW + i0 + ch * 8) = v;
  }

  if (it != jt) {
    __syncthreads();  // WAR: store-1 reads done before refill
    #pragma unroll
    for (int m = 0; m < 4; ++m) {
      #pragma unroll
      for (int n = 0; n < 4; ++n) {
        int il  = wi * 64 + n * 16 + lr;
        int jl0 = wj * 64 + m * 16 + lk * 4;
        unsigned long long pk =
            (unsigned long long)f16key(__half_as_ushort(__float2half(acc[m][n][0]))) |
            ((unsigned long long)f16key(__half_as_ushort(__float2half(acc[m][n][1]))) << 16) |
            ((unsigned long long)f16key(__half_as_ushort(__float2half(acc[m][n][2]))) << 32) |
            ((unsigned long long)f16key(__half_as_ushort(__float2half(acc[m][n][3]))) << 48);
        *(unsigned long long*)&tile[il * TPAD + jl0] = pk;
      }
    }
    __syncthreads();

    // store 2: mirror rows i of gk
    #pragma unroll
    for (int itr = 0; itr < 8; ++itr) {
      int idx = itr * 256 + tid;
      int row = idx >> 4, ch = idx & 15;
      u32x4 v = *(const u32x4*)&tile[row * TPAD + ch * 8];
      *(u32x4*)(gk + (size_t)(i0 + row) * HW + j0 + ch * 8) = v;
    }
  }
}

// ---------- kernel B: per-column top-115, SWAR packed counting ----------
// Keys stay PACKED in 8 u32x4 (32 VGPRs — register-resident, R11 verified).
// Corr in [-1.008,1.008] => keys in 15-bit space after -0x4000.
__launch_bounds__(256, 4)
__global__ void select_kernel(const unsigned short* __restrict__ gkeys,
                              float* __restrict__ out, int b_base, int nb) {
  __shared__ unsigned short cand[4][CAND];
  __shared__ unsigned int cnt[4];
  const int tid  = threadIdx.x;
  const int lane = tid & 63, wv = tid >> 6;
  int bb, cg;
  if (nb == 4) {
    const int xcd = blockIdx.x & 7;
    bb = xcd >> 1;
    cg = ((xcd & 1) << 9) + (blockIdx.x >> 3);   // [0,1024)
  } else {
    bb = 0;
    cg = blockIdx.x;
  }
  const int b = b_base + bb;
  const int j = cg * 4 + wv;

  const u32x4* cp4 = (const u32x4*)(gkeys + (size_t)bb * HW * HW + (size_t)j * HW);
  u32x4 q0 = cp4[0 * 64 + lane], q1 = cp4[1 * 64 + lane];
  u32x4 q2 = cp4[2 * 64 + lane], q3 = cp4[3 * 64 + lane];
  u32x4 q4 = cp4[4 * 64 + lane], q5 = cp4[5 * 64 + lane];
  u32x4 q6 = cp4[6 * 64 + lane], q7 = cp4[7 * 64 + lane];

  // one-time SWAR transform (keys remain recoverable: half & 0x7fff)
  q0 = (q0 - 0x40004000u) | 0x80008000u;
  q1 = (q1 - 0x40004000u) | 0x80008000u;
  q2 = (q2 - 0x40004000u) | 0x80008000u;
  q3 = (q3 - 0x40004000u) | 0x80008000u;
  q4 = (q4 - 0x40004000u) | 0x80008000u;
  q5 = (q5 - 0x40004000u) | 0x80008000u;
  q6 = (q6 - 0x40004000u) | 0x80008000u;
  q7 = (q7 - 0x40004000u) | 0x80008000u;

  // binary search in 15-bit space: lo = max v with #{k15 >= v} >= 115
  unsigned int lo = 0;
  #pragma unroll 1
  for (int bit = 14; bit >= 0; --bit) {
    const unsigned int m  = lo | (1u << bit);
    const unsigned int mm = m * 0x10001u;
    int c = 0;
    #define CNTV(Q) \
      c += (int)__builtin_popcount((Q.x - mm) & 0x80008000u); \
      c += (int)__builtin_popcount((Q.y - mm) & 0x80008000u); \
      c += (int)__builtin_popcount((Q.z - mm) & 0x80008000u); \
      c += (int)__builtin_popcount((Q.w - mm) & 0x80008000u);
    CNTV(q0) CNTV(q1) CNTV(q2) CNTV(q3)
    CNTV(q4) CNTV(q5) CNTV(q6) CNTV(q7)
    #undef CNTV
    c += __shfl_xor(c, 1);
    c += __shfl_xor(c, 2);
    c += __shfl_xor(c, 4);
    c += __shfl_xor(c, 8);
    c += __shfl_xor(c, 16);
    c += __shfl_xor(c, 32);
    if (c >= K_TOP) lo = m;
  }

  // prefill candidates with threshold (15-bit values; u16-typed — TBAA!)
  cand[wv][2 * lane]     = (unsigned short)lo;
  cand[wv][2 * lane + 1] = (unsigned short)lo;
  if (lane == 0) cnt[wv] = 0;

  // scatter strictly-greater 15-bit keys (<=114 guaranteed)
  #define GATH(v)                                                \
    { unsigned int _v = (v);                                     \
      if (_v > lo) {                                             \
        unsigned int _p = atomicAdd(&cnt[wv], 1u);               \
        cand[wv][_p] = (unsigned short)_v;                       \
      } }
  #define GATH4(Q)                                               \
    GATH(Q.x & 0x7fffu) GATH((Q.x >> 16) & 0x7fffu)              \
    GATH(Q.y & 0x7fffu) GATH((Q.y >> 16) & 0x7fffu)              \
    GATH(Q.z & 0x7fffu) GATH((Q.z >> 16) & 0x7fffu)              \
    GATH(Q.w & 0x7fffu) GATH((Q.w >> 16) & 0x7fffu)
  GATH4(q0) GATH4(q1) GATH4(q2) GATH4(q3)
  GATH4(q4) GATH4(q5) GATH4(q6) GATH4(q7)
  #undef GATH4
  #undef GATH

  asm volatile("" ::: "memory");  // scatter stores before read-back

  // rank-by-count over 128 candidates (unique composite keys -> unique ranks)
  unsigned int k0 = cand[wv][2 * lane];
  unsigned int k1 = cand[wv][2 * lane + 1];
  unsigned int c0 = (k0 << 7) | (127u - (unsigned)(2 * lane));
  unsigned int c1 = (k1 << 7) | (127u - (unsigned)(2 * lane + 1));
  int r0 = 0, r1 = 0;
  #pragma unroll 1
  for (int sl = 0; sl < 64; ++sl) {
    unsigned int d0 = __shfl(c0, sl);
    unsigned int d1 = __shfl(c1, sl);
    r0 += (int)(d0 > c0) + (int)(d1 > c0);
    r1 += (int)(d0 > c1) + (int)(d1 > c1);
  }
  if (r0 < K_TOP)
    out[((size_t)b * K_TOP + r0) * HW + j] =
        __half2float(__ushort_as_half(key2f16(k0 + 0x4000u))) * (1.0f / 256.0f);
  if (r1 < K_TOP)
    out[((size_t)b * K_TOP + r1) * HW + j] =
        __half2float(__ushort_as_half(key2f16(k1 + 0x4000u))) * (1.0f / 256.0f);
}

extern "C" void kernel_launch(void* const* d_in, const int* in_sizes, int n_in,
                              void* d_out, int out_size, void* d_ws, size_t ws_size,
                              hipStream_t stream) {
  (void)in_sizes; (void)n_in; (void)out_size;
  const float* x = (const float*)d_in[0];
  float* out = (float*)d_out;
  float* rn = (float*)d_ws;                                       // 64 KB
  unsigned short* xnT = (unsigned short*)((char*)d_ws + 65536);   // 8 MB bf16
  const size_t GK_OFF = 65536 + (size_t)8 * 1024 * 1024;
  const size_t ONE    = (size_t)HW * HW * 2;                      // 32 MB / batch
  const size_t NEED_1 = GK_OFF + ONE;
  const size_t NEED_4 = GK_OFF + 4 * ONE;                         // 136 MB

  norms_kernel<<<64, 256, 0, stream>>>(x, rn);
  transpose_kernel<<<1024, 256, 0, stream>>>(x, rn, xnT);

  if (ws_size >= NEED_4) {
    unsigned short* gkeys = (unsigned short*)((char*)d_ws + GK_OFF);
    gram_kernel<<<4 * NTRI, 256, 0, stream>>>(xnT, gkeys, 4);
    select_kernel<<<4096, 256, 0, stream>>>(gkeys, out, 0, 4);
  } else if (ws_size >= NEED_1) {
    unsigned short* gkeys = (unsigned short*)((char*)d_ws + GK_OFF);
    for (int b = 0; b < 4; ++b) {
      gram_kernel<<<NTRI, 256, 0, stream>>>(xnT + (size_t)b * HW * CH, gkeys, 1);
      select_kernel<<<1024, 256, 0, stream>>>(gkeys, out, b, 1);
    }
  }
}

// Round 15
// 135.781 us; speedup vs baseline: 3.0992x; 1.0052x over previous
//
#include <hip/hip_runtime.h>
#include <hip/hip_fp16.h>

#define CH 256
#define HW 4096
#define K_TOP 115
#define CAND 128
#define TPAD 152   // u16 row stride: 304B; 4-row offset = 16 mod 32 -> 2-way (free); rows 16B-aligned
#define NTRI 528   // 32*33/2 upper-triangle 128x128 tiles per batch
#define NTRI_H 264 // half-triangle per XCD

typedef __attribute__((ext_vector_type(8))) short short8;
typedef __attribute__((ext_vector_type(4))) float f32x4;
typedef __attribute__((ext_vector_type(4))) unsigned int u32x4;

__device__ __forceinline__ unsigned short f32_to_bf16(float f) {
  union { float f; unsigned int u; } v; v.f = f;
  unsigned int r = v.u + 0x7fffu + ((v.u >> 16) & 1u);
  return (unsigned short)(r >> 16);
}

__device__ __forceinline__ unsigned int f16key(unsigned short h) {
  return (h & 0x8000u) ? (unsigned int)((unsigned short)~h)
                       : (unsigned int)(h | 0x8000u);
}

__device__ __forceinline__ unsigned short key2f16(unsigned int k) {
  return (k & 0x8000u) ? (unsigned short)(k ^ 0x8000u)
                       : (unsigned short)(~k & 0xffffu);
}

// ---------- kernel 1a: rn[b][p] = 1 / max(||x[b,:,p]||, eps) ----------
__global__ void norms_kernel(const float* __restrict__ x, float* __restrict__ rn) {
  int b = blockIdx.x >> 4;
  int p = ((blockIdx.x & 15) << 8) + threadIdx.x;
  const float* xb = x + (size_t)b * CH * HW + p;
  float ss = 0.f;
  #pragma unroll 8
  for (int c = 0; c < CH; ++c) { float v = xb[(size_t)c * HW]; ss += v * v; }
  rn[b * HW + p] = 1.0f / fmaxf(sqrtf(ss), 1e-12f);
}

// ---------- kernel 1b: xnT in FRAGMENT-MAJOR layout ----------
// xnT[b][pg:256][kk:8][lane:64] = 16B entry: pixel pg*16+(lane&15),
// channels kk*32+(lane>>4)*8 .. +8, bf16. A wave's MFMA fragment load is
// 64 lanes x 16B CONTIGUOUS (1KB) — R14: gram 87.5 -> ~40us (TA-bound fix).
__global__ void transpose_kernel(const float* __restrict__ x, const float* __restrict__ rn,
                                 unsigned short* __restrict__ xnT) {
  __shared__ float tile[64][65];   // [c_local][p_local]
  int blk = blockIdx.x;
  int b = blk >> 8;
  int rem = blk & 255;
  int c0 = (rem >> 6) << 6;
  int p0 = (rem & 63) << 6;
  for (int idx = threadIdx.x; idx < 64 * 64; idx += blockDim.x) {
    int c = idx >> 6, p = idx & 63;
    tile[c][p] = x[((size_t)b * CH + c0 + c) * HW + p0 + p];
  }
  __syncthreads();
  for (int E = threadIdx.x; E < 512; E += blockDim.x) {
    int lr  = E & 15;
    int lk  = (E >> 4) & 3;
    int kkl = (E >> 6) & 1;
    int pgl = E >> 7;
    int pl = pgl * 16 + lr;
    int cl = kkl * 32 + lk * 8;
    float s = rn[b * HW + p0 + pl];
    unsigned int w0, w1, w2, w3;
    w0 = (unsigned int)f32_to_bf16(tile[cl + 0][pl] * s) |
         ((unsigned int)f32_to_bf16(tile[cl + 1][pl] * s) << 16);
    w1 = (unsigned int)f32_to_bf16(tile[cl + 2][pl] * s) |
         ((unsigned int)f32_to_bf16(tile[cl + 3][pl] * s) << 16);
    w2 = (unsigned int)f32_to_bf16(tile[cl + 4][pl] * s) |
         ((unsigned int)f32_to_bf16(tile[cl + 5][pl] * s) << 16);
    w3 = (unsigned int)f32_to_bf16(tile[cl + 6][pl] * s) |
         ((unsigned int)f32_to_bf16(tile[cl + 7][pl] * s) << 16);
    u32x4 w = {w0, w1, w2, w3};
    int pg  = (p0 >> 4) + pgl;
    int kkg = (c0 >> 5) + kkl;
    *(u32x4*)(xnT + ((((size_t)b * 256 + pg) * 8 + kkg) * 64 + lk * 16 + lr) * 8) = w;
  }
}

// ---------- kernel A: symmetric Gram -> u16 keys (row-major per batch) ----------
__launch_bounds__(256, 4)
__global__ void gram_kernel(const unsigned short* __restrict__ xnT,
                            unsigned short* __restrict__ gkeys, int nb) {
  __shared__ unsigned short tile[128 * TPAD];
  const int tid  = threadIdx.x;
  const int lane = tid & 63, wv = tid >> 6;
  const int wj = wv >> 1, wi = wv & 1;
  const int lr = lane & 15, lk = lane >> 4;

  int bb, t;
  if (nb == 4) {
    const int xcd = blockIdx.x & 7;
    bb = xcd >> 1;
    t  = ((xcd & 1) ? NTRI_H : 0) + (blockIdx.x >> 3);
  } else {
    bb = 0;
    t  = blockIdx.x;
  }
  int it = (int)((sqrtf(8.0f * (float)t + 1.0f) - 1.0f) * 0.5f);
  while (((it + 1) * (it + 2)) / 2 <= t) ++it;
  while ((it * (it + 1)) / 2 > t) --it;
  const int jt = t - (it * (it + 1)) / 2;  // jt <= it
  const int j0 = jt * 128, i0 = it * 128;

  const short8* x8 = (const short8*)(xnT + (size_t)bb * HW * CH);
  unsigned short* gk = gkeys + (size_t)bb * HW * HW;

  f32x4 acc[4][4];
  #pragma unroll
  for (int m = 0; m < 4; ++m)
    #pragma unroll
    for (int n = 0; n < 4; ++n) acc[m][n] = (f32x4){0.f, 0.f, 0.f, 0.f};

  // fragment-major: entry ((pg*8 + kk)*64 + lane), pg = pixel/16
  const int pgj = jt * 8 + wj * 4;
  const int pgi = it * 8 + wi * 4;
  #pragma unroll
  for (int kk = 0; kk < 8; ++kk) {
    short8 af[4], bf[4];
    #pragma unroll
    for (int m = 0; m < 4; ++m)
      af[m] = x8[(size_t)((pgj + m) * 8 + kk) * 64 + lane];
    #pragma unroll
    for (int n = 0; n < 4; ++n)
      bf[n] = x8[(size_t)((pgi + n) * 8 + kk) * 64 + lane];
    #pragma unroll
    for (int m = 0; m < 4; ++m)
      #pragma unroll
      for (int n = 0; n < 4; ++n)
        acc[m][n] = __builtin_amdgcn_mfma_f32_16x16x32_bf16(af[m], bf[n],
                                                            acc[m][n], 0, 0, 0);
  }

  // phase 1: keys -> tile[jloc][iloc]  (D row = j, D col = i)
  #pragma unroll
  for (int m = 0; m < 4; ++m) {
    #pragma unroll
    for (int n = 0; n < 4; ++n) {
      #pragma unroll
      for (int r = 0; r < 4; ++r) {
        int jloc = wj * 64 + m * 16 + lk * 4 + r;
        int iloc = wi * 64 + n * 16 + lr;
        tile[jloc * TPAD + iloc] =
            (unsigned short)f16key(__half_as_ushort(__float2half(acc[m][n][r])));
      }
    }
  }
  __syncthreads();

  // store 1: rows j of gk (coalesced 16B chunks)
  #pragma unroll
  for (int itr = 0; itr < 8; ++itr) {
    int idx = itr * 256 + tid;
    int row = idx >> 4, ch = idx & 15;
    u32x4 v = *(const u32x4*)&tile[row * TPAD + ch * 8];
    *(u32x4*)(gk + (size_t)(j0 + row) * HW + i0 + ch * 8) = v;
  }

  if (it != jt) {
    __syncthreads();  // WAR: store-1 reads done before refill
    #pragma unroll
    for (int m = 0; m < 4; ++m) {
      #pragma unroll
      for (int n = 0; n < 4; ++n) {
        int il  = wi * 64 + n * 16 + lr;
        int jl0 = wj * 64 + m * 16 + lk * 4;
        unsigned long long pk =
            (unsigned long long)f16key(__half_as_ushort(__float2half(acc[m][n][0]))) |
            ((unsigned long long)f16key(__half_as_ushort(__float2half(acc[m][n][1]))) << 16) |
            ((unsigned long long)f16key(__half_as_ushort(__float2half(acc[m][n][2]))) << 32) |
            ((unsigned long long)f16key(__half_as_ushort(__float2half(acc[m][n][3]))) << 48);
        *(unsigned long long*)&tile[il * TPAD + jl0] = pk;
      }
    }
    __syncthreads();

    // store 2: mirror rows i of gk
    #pragma unroll
    for (int itr = 0; itr < 8; ++itr) {
      int idx = itr * 256 + tid;
      int row = idx >> 4, ch = idx & 15;
      u32x4 v = *(const u32x4*)&tile[row * TPAD + ch * 8];
      *(u32x4*)(gk + (size_t)(i0 + row) * HW + j0 + ch * 8) = v;
    }
  }
}

// ---------- kernel B: per-column top-115, SWAR count + O(1)-depth rank ----------
// Search unchanged (R11). NEW rank (R14: 64-iter shfl-broadcast loop = 128
// dependency-chained ds_bpermutes dominated select): (1) strict-greater count
// g via SWAR vs broadcast LDS reads of the candidate pairs (16 independent
// ds_read_b128, wave-uniform addr -> conflict-free); (2) ties get dense
// unique ranks via atomicAdd(&rcnt[g]) offset (equal keys share g; group of
// t fills ranks g..g+t-1).
__launch_bounds__(256, 4)
__global__ void select_kernel(const unsigned short* __restrict__ gkeys,
                              float* __restrict__ out, int b_base, int nb) {
  __shared__ __align__(16) unsigned short cand[4][CAND];
  __shared__ unsigned int rcnt[4][CAND];
  __shared__ unsigned int cnt[4];
  const int tid  = threadIdx.x;
  const int lane = tid & 63, wv = tid >> 6;
  int bb, cg;
  if (nb == 4) {
    const int xcd = blockIdx.x & 7;
    bb = xcd >> 1;
    cg = ((xcd & 1) << 9) + (blockIdx.x >> 3);   // [0,1024)
  } else {
    bb = 0;
    cg = blockIdx.x;
  }
  const int b = b_base + bb;
  const int j = cg * 4 + wv;

  const u32x4* cp4 = (const u32x4*)(gkeys + (size_t)bb * HW * HW + (size_t)j * HW);
  u32x4 q0 = cp4[0 * 64 + lane], q1 = cp4[1 * 64 + lane];
  u32x4 q2 = cp4[2 * 64 + lane], q3 = cp4[3 * 64 + lane];
  u32x4 q4 = cp4[4 * 64 + lane], q5 = cp4[5 * 64 + lane];
  u32x4 q6 = cp4[6 * 64 + lane], q7 = cp4[7 * 64 + lane];

  // one-time SWAR transform (keys recoverable: half & 0x7fff)
  q0 = (q0 - 0x40004000u) | 0x80008000u;
  q1 = (q1 - 0x40004000u) | 0x80008000u;
  q2 = (q2 - 0x40004000u) | 0x80008000u;
  q3 = (q3 - 0x40004000u) | 0x80008000u;
  q4 = (q4 - 0x40004000u) | 0x80008000u;
  q5 = (q5 - 0x40004000u) | 0x80008000u;
  q6 = (q6 - 0x40004000u) | 0x80008000u;
  q7 = (q7 - 0x40004000u) | 0x80008000u;

  // binary search in 15-bit space: lo = max v with #{k15 >= v} >= 115
  unsigned int lo = 0;
  #pragma unroll 1
  for (int bit = 14; bit >= 0; --bit) {
    const unsigned int m  = lo | (1u << bit);
    const unsigned int mm = m * 0x10001u;
    int c = 0;
    #define CNTV(Q) \
      c += (int)__builtin_popcount((Q.x - mm) & 0x80008000u); \
      c += (int)__builtin_popcount((Q.y - mm) & 0x80008000u); \
      c += (int)__builtin_popcount((Q.z - mm) & 0x80008000u); \
      c += (int)__builtin_popcount((Q.w - mm) & 0x80008000u);
    CNTV(q0) CNTV(q1) CNTV(q2) CNTV(q3)
    CNTV(q4) CNTV(q5) CNTV(q6) CNTV(q7)
    #undef CNTV
    c += __shfl_xor(c, 1);
    c += __shfl_xor(c, 2);
    c += __shfl_xor(c, 4);
    c += __shfl_xor(c, 8);
    c += __shfl_xor(c, 16);
    c += __shfl_xor(c, 32);
    if (c >= K_TOP) lo = m;
  }

  // prefill candidates with threshold; zero rank-offset table
  cand[wv][2 * lane]     = (unsigned short)lo;
  cand[wv][2 * lane + 1] = (unsigned short)lo;
  rcnt[wv][2 * lane]     = 0;
  rcnt[wv][2 * lane + 1] = 0;
  if (lane == 0) cnt[wv] = 0;

  // scatter strictly-greater 15-bit keys (<=114 guaranteed)
  #define GATH(v)                                                \
    { unsigned int _v = (v);                                     \
      if (_v > lo) {                                             \
        unsigned int _p = atomicAdd(&cnt[wv], 1u);               \
        cand[wv][_p] = (unsigned short)_v;                       \
      } }
  #define GATH4(Q)                                               \
    GATH(Q.x & 0x7fffu) GATH((Q.x >> 16) & 0x7fffu)              \
    GATH(Q.y & 0x7fffu) GATH((Q.y >> 16) & 0x7fffu)              \
    GATH(Q.z & 0x7fffu) GATH((Q.z >> 16) & 0x7fffu)              \
    GATH(Q.w & 0x7fffu) GATH((Q.w >> 16) & 0x7fffu)
  GATH4(q0) GATH4(q1) GATH4(q2) GATH4(q3)
  GATH4(q4) GATH4(q5) GATH4(q6) GATH4(q7)
  #undef GATH4
  #undef GATH

  __syncthreads();  // full fence: scatter stores visible before u32 re-read

  // strict-greater count g for this lane's two candidates (SWAR, broadcast reads)
  unsigned int k0 = cand[wv][2 * lane];
  unsigned int k1 = cand[wv][2 * lane + 1];
  const unsigned int t0 = (k0 + 1u) * 0x10001u;
  const unsigned int t1 = (k1 + 1u) * 0x10001u;
  int g0 = 0, g1 = 0;
  {
    const u32x4* cv = (const u32x4*)&cand[wv][0];
    #pragma unroll
    for (int r = 0; r < 16; ++r) {
      u32x4 p = cv[r];
      #define GCNT(W) { unsigned int Pt = (W) | 0x80008000u;                 \
        g0 += (int)__builtin_popcount((Pt - t0) & 0x80008000u);              \
        g1 += (int)__builtin_popcount((Pt - t1) & 0x80008000u); }
      GCNT(p.x) GCNT(p.y) GCNT(p.z) GCNT(p.w)
      #undef GCNT
    }
  }
  // dense unique ranks for tie groups
  unsigned int o0 = atomicAdd(&rcnt[wv][g0], 1u);
  unsigned int o1 = atomicAdd(&rcnt[wv][g1], 1u);
  int r0 = g0 + (int)o0;
  int r1 = g1 + (int)o1;

  if (r0 < K_TOP)
    out[((size_t)b * K_TOP + r0) * HW + j] =
        __half2float(__ushort_as_half(key2f16(k0 + 0x4000u))) * (1.0f / 256.0f);
  if (r1 < K_TOP)
    out[((size_t)b * K_TOP + r1) * HW + j] =
        __half2float(__ushort_as_half(key2f16(k1 + 0x4000u))) * (1.0f / 256.0f);
}

extern "C" void kernel_launch(void* const* d_in, const int* in_sizes, int n_in,
                              void* d_out, int out_size, void* d_ws, size_t ws_size,
                              hipStream_t stream) {
  (void)in_sizes; (void)n_in; (void)out_size;
  const float* x = (const float*)d_in[0];
  float* out = (float*)d_out;
  float* rn = (float*)d_ws;                                       // 64 KB
  unsigned short* xnT = (unsigned short*)((char*)d_ws + 65536);   // 8 MB bf16
  const size_t GK_OFF = 65536 + (size_t)8 * 1024 * 1024;
  const size_t ONE    = (size_t)HW * HW * 2;                      // 32 MB / batch
  const size_t NEED_1 = GK_OFF + ONE;
  const size_t NEED_4 = GK_OFF + 4 * ONE;                         // 136 MB

  norms_kernel<<<64, 256, 0, stream>>>(x, rn);
  transpose_kernel<<<1024, 256, 0, stream>>>(x, rn, xnT);

  if (ws_size >= NEED_4) {
    unsigned short* gkeys = (unsigned short*)((char*)d_ws + GK_OFF);
    gram_kernel<<<4 * NTRI, 256, 0, stream>>>(xnT, gkeys, 4);
    select_kernel<<<4096, 256, 0, stream>>>(gkeys, out, 0, 4);
  } else if (ws_size >= NEED_1) {
    unsigned short* gkeys = (unsigned short*)((char*)d_ws + GK_OFF);
    for (int b = 0; b < 4; ++b) {
      gram_kernel<<<NTRI, 256, 0, stream>>>(xnT + (size_t)b * HW * CH, gkeys, 1);
      select_kernel<<<1024, 256, 0, stream>>>(gkeys, out, b, 1);
    }
  }
}